// Round 2
// baseline (1260.614 us; speedup 1.0000x reference)
//
#include <hip/hip_runtime.h>

// EdgeConvBlock: B=32, N=1024, D=3, CIN=64, K=16, COUT=128x3
// Round 2: single y buffer (in-place layers 1/2), ws guard + sentinel.

#define BB 32
#define NN 1024
#define CINC 64
#define KK 16
#define CO 128
#define NROW (BB*NN*KK)   // 524288
#define NROWSC (BB*NN)    // 32768

// ---- ws layout (bytes) ----
static const size_t OFF_FT   = 0;            // featsT f32 [B][N][64]       8,388,608
static const size_t OFF_IDX  = 8388608;      // idx int  [B][N][16]         2,097,152
static const size_t OFF_Y    = 10485760;     // y  bf16  [NROW][128]      134,217,728
static const size_t OFF_SC   = 144703488;    // sc f32   [NROWSC][128]     16,777,216
static const size_t OFF_PART = 161480704;    // partials f32 [8192][256]    8,388,608
static const size_t OFF_S1   = 169869312;    // stage1 f32 [64][256]           65,536
static const size_t OFF_SB   = 169934848;    // scale/bias f32 [4][256]         4,096
static const size_t WS_NEED  = 169938944;

__device__ __forceinline__ float bl(unsigned u){ return __uint_as_float(u<<16); }
__device__ __forceinline__ float bh(unsigned u){ return __uint_as_float(u & 0xffff0000u); }
__device__ __forceinline__ unsigned short bfr(float x){
  unsigned u = __float_as_uint(x);
  u += 0x7fffu + ((u>>16)&1u);
  return (unsigned short)(u>>16);
}

// ---------------- diagnostic sentinel ----------------
__global__ __launch_bounds__(256) void sentinel_kernel(float* __restrict__ out, int n, float v){
  int i = blockIdx.x*256 + threadIdx.x;
  if (i < n) out[i] = v;
}

// ---------------- transpose features (b,c,n) -> (b,n,c) ----------------
__global__ __launch_bounds__(256) void transpose_feats(const float* __restrict__ f,
                                                       float* __restrict__ ft){
  __shared__ __align__(16) float tile[64][65];
  int t = threadIdx.x;
  int b = blockIdx.x, n0 = blockIdx.y*64;
  for (int it=0; it<16; ++it){
    int flat = it*256 + t;
    int c = flat>>6, nl = flat&63;
    tile[c][nl] = f[(b*64 + c)*1024 + n0 + nl];
  }
  __syncthreads();
  for (int it=0; it<16; ++it){
    int flat = it*256 + t;
    int nl = flat>>6, c = flat&63;
    ft[((b<<10) + n0 + nl)*64 + c] = tile[c][nl];
  }
}

// ---------------- KNN: top-16 by pd = 2*inner - xx_n - xx_m, self excluded ----------------
__global__ __launch_bounds__(256) void knn_kernel(const float* __restrict__ pts,
                                                  int* __restrict__ idxout){
  __shared__ __align__(16) float px[1024], py[1024], pz[1024], xx[1024];
  int t = threadIdx.x;
  int b = blockIdx.x;
  for (int i=t; i<1024; i+=256){
    float a = pts[(b*3+0)*1024+i];
    float c = pts[(b*3+1)*1024+i];
    float d = pts[(b*3+2)*1024+i];
    px[i]=a; py[i]=c; pz[i]=d;
    xx[i] = __fadd_rn(__fadd_rn(__fmul_rn(a,a), __fmul_rn(c,c)), __fmul_rn(d,d));
  }
  __syncthreads();
  int n = blockIdx.y*256 + t;
  float qx=px[n], qy=py[n], qz=pz[n], qxx=xx[n];
  float vals[16]; int idxs[16];
  #pragma unroll
  for (int j=0;j<16;++j){ vals[j] = -3.4e38f; idxs[j] = 0; }
  for (int m=0; m<1024; ++m){
    // match np: mul+add (no fma), then (2*inner - xx_n) - xx_m
    float inner = __fadd_rn(__fadd_rn(__fmul_rn(qx,px[m]), __fmul_rn(qy,py[m])), __fmul_rn(qz,pz[m]));
    float pd = __fsub_rn(__fsub_rn(__fmul_rn(2.0f, inner), qxx), xx[m]);
    if (m != n && pd > vals[15]){
      float cv = pd; int ci = m;
      #pragma unroll
      for (int j=0;j<16;++j){
        bool take = cv > vals[j];      // strict: ties keep existing (lower index)
        float ov = vals[j]; int oi = idxs[j];
        vals[j] = take ? cv : ov;  idxs[j] = take ? ci : oi;
        cv      = take ? ov : cv;  ci      = take ? oi : ci;
      }
    }
  }
  #pragma unroll
  for (int j=0;j<16;++j) idxout[((b<<10)+n)*16 + j] = idxs[j];
}

// ---------------- GEMM: [64 rows x 128 out], bf16 operands, f32 accum ----------------
// MODE 0: x gathered from featsT via knn (center || nbr-center)
// MODE 1: x = relu(yin*scale + bias), yin bf16 (safe in-place: block reads only
//         its own 64 rows into LDS before writing the same 64 rows)
template<int MODE>
__global__ __launch_bounds__(256) void gemm_kernel(const float* __restrict__ featsT,
                                                   const int* __restrict__ knn,
                                                   const unsigned short* __restrict__ yin,
                                                   const float* __restrict__ sb,
                                                   const float* __restrict__ W,
                                                   unsigned short* __restrict__ yout,
                                                   float* __restrict__ partials){
  __shared__ __align__(16) unsigned short Wt[128][136];
  __shared__ __align__(16) unsigned short xs[64][136];
  __shared__ __align__(16) float cen[4][64];
  __shared__ __align__(16) int midx[64];
  int t = threadIdx.x;
  int tx = t & 15, ty = t >> 4;
  int rowbase = blockIdx.x * 64;

  // stage W (o-major global) -> Wt[c][o] bf16
  for (int it=0; it<64; ++it){
    int flat = it*256 + t;
    int o = flat >> 7, c = flat & 127;
    Wt[c][o] = bfr(W[flat]);
  }
  if constexpr (MODE == 0){
    (void)yin; (void)sb;
    int b  = rowbase >> 14;            // 16384 rows per batch
    int n0 = (rowbase >> 4) & 1023;
    if (t < 64) midx[t] = knn[rowbase + t];
    { int i = t>>6, c = t&63; cen[i][c] = featsT[((b<<10) + n0 + i)*64 + c]; }
    __syncthreads();
    for (int it=0; it<16; ++it){
      int flat = it*256 + t;
      int r = flat>>6, c = flat&63;
      float cv = cen[r>>4][c];
      float nv = featsT[((b<<10) + midx[r])*64 + c];
      xs[r][c]    = bfr(cv);
      xs[r][64+c] = bfr(nv - cv);
    }
  } else {
    (void)featsT; (void)knn;
    const uint2* yv = reinterpret_cast<const uint2*>(yin);
    for (int it=0; it<8; ++it){
      int flat = it*256 + t;
      int r = flat>>5, q = flat&31;
      uint2 v = yv[(size_t)(rowbase + r)*32 + q];
      int c = q*4;
      float f0 = bl(v.x), f1 = bh(v.x), f2 = bl(v.y), f3 = bh(v.y);
      f0 = fmaxf(fmaf(f0, sb[c+0], sb[128+c+0]), 0.f);
      f1 = fmaxf(fmaf(f1, sb[c+1], sb[128+c+1]), 0.f);
      f2 = fmaxf(fmaf(f2, sb[c+2], sb[128+c+2]), 0.f);
      f3 = fmaxf(fmaf(f3, sb[c+3], sb[128+c+3]), 0.f);
      xs[r][c+0] = bfr(f0); xs[r][c+1] = bfr(f1);
      xs[r][c+2] = bfr(f2); xs[r][c+3] = bfr(f3);
    }
  }
  __syncthreads();

  float acc[4][8] = {};
  for (int c=0; c<128; ++c){
    uint4 wv = *reinterpret_cast<const uint4*>(&Wt[c][tx*8]);
    float w[8];
    w[0]=bl(wv.x); w[1]=bh(wv.x); w[2]=bl(wv.y); w[3]=bh(wv.y);
    w[4]=bl(wv.z); w[5]=bh(wv.z); w[6]=bl(wv.w); w[7]=bh(wv.w);
    #pragma unroll
    for (int i=0;i<4;++i){
      float xv = bl((unsigned)xs[ty*4+i][c]);
      #pragma unroll
      for (int j=0;j<8;++j) acc[i][j] = fmaf(xv, w[j], acc[i][j]);
    }
  }

  // store y as bf16 (packed 16B per thread-row)
  #pragma unroll
  for (int i=0;i<4;++i){
    uint4 o4;
    o4.x = (unsigned)bfr(acc[i][0]) | ((unsigned)bfr(acc[i][1])<<16);
    o4.y = (unsigned)bfr(acc[i][2]) | ((unsigned)bfr(acc[i][3])<<16);
    o4.z = (unsigned)bfr(acc[i][4]) | ((unsigned)bfr(acc[i][5])<<16);
    o4.w = (unsigned)bfr(acc[i][6]) | ((unsigned)bfr(acc[i][7])<<16);
    *reinterpret_cast<uint4*>(yout + (size_t)(rowbase + ty*4 + i)*128 + tx*8) = o4;
  }

  // block-level BN partial stats (deterministic)
  __syncthreads();                       // xs no longer needed
  float* red = reinterpret_cast<float*>(&xs[0][0]);   // 16*128 f32 = 8KB <= xs
  #pragma unroll
  for (int j=0;j<8;++j){
    float s = 0.f;
    #pragma unroll
    for (int i=0;i<4;++i) s += acc[i][j];
    red[ty*128 + tx*8 + j] = s;
  }
  __syncthreads();
  if (t < 128){
    float s = 0.f;
    for (int y2=0;y2<16;++y2) s += red[y2*128 + t];
    partials[(size_t)blockIdx.x*256 + t] = s;
  }
  __syncthreads();
  #pragma unroll
  for (int j=0;j<8;++j){
    float s = 0.f;
    #pragma unroll
    for (int i=0;i<4;++i) s += acc[i][j]*acc[i][j];
    red[ty*128 + tx*8 + j] = s;
  }
  __syncthreads();
  if (t < 128){
    float s = 0.f;
    for (int y2=0;y2<16;++y2) s += red[y2*128 + t];
    partials[(size_t)blockIdx.x*256 + 128 + t] = s;
  }
}

// ---------------- shortcut GEMM: feats(64) x Wsc^T -> sc f32 ----------------
__global__ __launch_bounds__(256) void sc_gemm(const float* __restrict__ featsT,
                                               const float* __restrict__ W,
                                               float* __restrict__ scout,
                                               float* __restrict__ partials){
  __shared__ __align__(16) unsigned short Wt[64][136];
  __shared__ __align__(16) unsigned short xs[64][72];
  int t = threadIdx.x, tx = t&15, ty = t>>4;
  int rowbase = blockIdx.x * 64;
  for (int it=0; it<32; ++it){
    int flat = it*256 + t;
    int o = flat>>6, c = flat&63;
    Wt[c][o] = bfr(W[flat]);
  }
  for (int it=0; it<16; ++it){
    int flat = it*256 + t;
    int r = flat>>6, c = flat&63;
    xs[r][c] = bfr(featsT[(size_t)(rowbase + r)*64 + c]);
  }
  __syncthreads();
  float acc[4][8] = {};
  for (int c=0;c<64;++c){
    uint4 wv = *reinterpret_cast<const uint4*>(&Wt[c][tx*8]);
    float w[8];
    w[0]=bl(wv.x); w[1]=bh(wv.x); w[2]=bl(wv.y); w[3]=bh(wv.y);
    w[4]=bl(wv.z); w[5]=bh(wv.z); w[6]=bl(wv.w); w[7]=bh(wv.w);
    #pragma unroll
    for (int i=0;i<4;++i){
      float xv = bl((unsigned)xs[ty*4+i][c]);
      #pragma unroll
      for (int j=0;j<8;++j) acc[i][j] = fmaf(xv, w[j], acc[i][j]);
    }
  }
  #pragma unroll
  for (int i=0;i<4;++i)
    #pragma unroll
    for (int j=0;j<8;++j)
      scout[(size_t)(rowbase + ty*4 + i)*128 + tx*8 + j] = acc[i][j];

  __syncthreads();
  float* red = reinterpret_cast<float*>(&xs[0][0]);   // 8KB <= 9216B
  #pragma unroll
  for (int j=0;j<8;++j){
    float s=0.f;
    #pragma unroll
    for (int i=0;i<4;++i) s += acc[i][j];
    red[ty*128 + tx*8 + j] = s;
  }
  __syncthreads();
  if (t<128){
    float s=0.f;
    for (int y2=0;y2<16;++y2) s += red[y2*128 + t];
    partials[(size_t)blockIdx.x*256 + t] = s;
  }
  __syncthreads();
  #pragma unroll
  for (int j=0;j<8;++j){
    float s=0.f;
    #pragma unroll
    for (int i=0;i<4;++i) s += acc[i][j]*acc[i][j];
    red[ty*128 + tx*8 + j] = s;
  }
  __syncthreads();
  if (t<128){
    float s=0.f;
    for (int y2=0;y2<16;++y2) s += red[y2*128 + t];
    partials[(size_t)blockIdx.x*256 + 128 + t] = s;
  }
}

// ---------------- deterministic stat reduction ----------------
__global__ __launch_bounds__(256) void reduce_stage1(const float* __restrict__ partials,
                                                     float* __restrict__ out, int rows){
  int t = threadIdx.x;
  size_t base = (size_t)blockIdx.x * rows * 256;
  float acc = 0.f;
  for (int r=0;r<rows;++r) acc += partials[base + (size_t)r*256 + t];
  out[blockIdx.x*256 + t] = acc;
}

__global__ __launch_bounds__(256) void finalize_stats(const float* __restrict__ s1, int g1,
                                                      float inv_count,
                                                      const float* __restrict__ g,
                                                      const float* __restrict__ beta,
                                                      float* __restrict__ sb){
  int t = threadIdx.x;
  float acc = 0.f;
  for (int j=0;j<g1;++j) acc += s1[j*256 + t];
  __shared__ float tot[256];
  tot[t] = acc;
  __syncthreads();
  if (t < 128){
    float mean = tot[t] * inv_count;
    float var  = tot[128+t] * inv_count - mean*mean;
    var = fmaxf(var, 0.f);
    float rstd = 1.0f / sqrtf(var + 1e-5f);
    float s = g[t] * rstd;
    sb[t] = s;
    sb[128+t] = beta[t] - mean*s;
  }
}

// ---------------- final: out = relu(bn_sc(sc) + mean_k relu(bn2(y2))) , transposed ----------------
__global__ __launch_bounds__(256) void final_kernel(const unsigned short* __restrict__ y2,
                                                    const float* __restrict__ sc,
                                                    const float* __restrict__ sb2,
                                                    const float* __restrict__ sbsc,
                                                    float* __restrict__ out){
  __shared__ __align__(16) float obuf[128][66];
  int t = threadIdx.x;
  int b = blockIdx.x >> 4;
  int n0 = (blockIdx.x & 15) * 64;
  int o = t & 127, half = t >> 7;
  float s2 = sb2[o], c2 = sb2[128+o];
  float ss = sbsc[o], cs = sbsc[128+o];
  for (int nn=0; nn<64; nn+=2){
    int nl = nn + half;
    size_t row0 = ((size_t)((b<<10) + n0 + nl)) << 4;
    float acc = 0.f;
    #pragma unroll
    for (int k=0;k<16;++k){
      float v = bl((unsigned)y2[(row0 + k)*128 + o]);
      acc += fmaxf(fmaf(v, s2, c2), 0.f);
    }
    float fts = acc * (1.f/16.f);
    float scv = sc[(size_t)((b<<10) + n0 + nl)*128 + o];
    scv = fmaf(scv, ss, cs);
    obuf[o][nl] = fmaxf(scv + fts, 0.f);
  }
  __syncthreads();
  for (int it=0; it<32; ++it){
    int flat = it*256 + t;
    int oo = flat>>6, nl = flat&63;
    out[((size_t)b<<17) + (oo<<10) + n0 + nl] = obuf[oo][nl];
  }
}

extern "C" void kernel_launch(void* const* d_in, const int* in_sizes, int n_in,
                              void* d_out, int out_size, void* d_ws, size_t ws_size,
                              hipStream_t stream) {
  const float* points   = (const float*)d_in[0];
  const float* features = (const float*)d_in[1];
  const float* W0  = (const float*)d_in[2];
  const float* g0  = (const float*)d_in[3];
  const float* b0  = (const float*)d_in[4];
  const float* W1  = (const float*)d_in[5];
  const float* g1  = (const float*)d_in[6];
  const float* b1  = (const float*)d_in[7];
  const float* W2  = (const float*)d_in[8];
  const float* g2  = (const float*)d_in[9];
  const float* b2  = (const float*)d_in[10];
  const float* Wsc = (const float*)d_in[11];
  const float* gsc = (const float*)d_in[12];
  const float* bsc = (const float*)d_in[13];

  float* out = (float*)d_out;

  // Diagnostic: if ws is too small, report its size (in MB) via absmax instead of faulting.
  if (ws_size < WS_NEED){
    float v = (float)(ws_size >> 20);
    sentinel_kernel<<<(out_size + 255)/256, 256, 0, stream>>>(out, out_size, v);
    return;
  }

  char* ws = (char*)d_ws;
  float*          featsT = (float*)(ws + OFF_FT);
  int*            idx    = (int*)(ws + OFF_IDX);
  unsigned short* y      = (unsigned short*)(ws + OFF_Y);
  float*          scbuf  = (float*)(ws + OFF_SC);
  float*          part   = (float*)(ws + OFF_PART);
  float*          s1     = (float*)(ws + OFF_S1);
  float*          sb     = (float*)(ws + OFF_SB);

  transpose_feats<<<dim3(32,16), 256, 0, stream>>>(features, featsT);
  knn_kernel<<<dim3(32,4), 256, 0, stream>>>(points, idx);

  // layer 0
  gemm_kernel<0><<<NROW/64, 256, 0, stream>>>(featsT, idx, nullptr, nullptr, W0, y, part);
  reduce_stage1<<<64, 256, 0, stream>>>(part, s1, 128);
  finalize_stats<<<1, 256, 0, stream>>>(s1, 64, 1.f/524288.f, g0, b0, sb + 0);
  // layer 1 (in-place)
  gemm_kernel<1><<<NROW/64, 256, 0, stream>>>(nullptr, nullptr, y, sb + 0, W1, y, part);
  reduce_stage1<<<64, 256, 0, stream>>>(part, s1, 128);
  finalize_stats<<<1, 256, 0, stream>>>(s1, 64, 1.f/524288.f, g1, b1, sb + 256);
  // layer 2 (in-place)
  gemm_kernel<1><<<NROW/64, 256, 0, stream>>>(nullptr, nullptr, y, sb + 256, W2, y, part);
  reduce_stage1<<<64, 256, 0, stream>>>(part, s1, 128);
  finalize_stats<<<1, 256, 0, stream>>>(s1, 64, 1.f/524288.f, g2, b2, sb + 512);
  // shortcut
  sc_gemm<<<NROWSC/64, 256, 0, stream>>>(featsT, Wsc, scbuf, part);
  reduce_stage1<<<8, 256, 0, stream>>>(part, s1, 64);
  finalize_stats<<<1, 256, 0, stream>>>(s1, 8, 1.f/32768.f, gsc, bsc, sb + 768);
  // fuse + transpose
  final_kernel<<<512, 256, 0, stream>>>(y, scbuf, sb + 512, sb + 768, out);
}

// Round 3
// 843.988 us; speedup vs baseline: 1.4936x; 1.4936x over previous
//
#include <hip/hip_runtime.h>

// EdgeConvBlock: B=32, N=1024, D=3, CIN=64, K=16, COUT=128x3
// Round 3: MFMA bf16 16x16x32 for the three big GEMMs.

#define BB 32
#define NN 1024
#define CINC 64
#define KK 16
#define CO 128
#define NROW (BB*NN*KK)   // 524288
#define NROWSC (BB*NN)    // 32768

// ---- ws layout (bytes) ----
static const size_t OFF_FT   = 0;            // featsT f32 [B][N][64]       8,388,608
static const size_t OFF_IDX  = 8388608;      // idx int  [B][N][16]         2,097,152
static const size_t OFF_Y    = 10485760;     // y  bf16  [NROW][128]      134,217,728
static const size_t OFF_SC   = 144703488;    // sc f32   [NROWSC][128]     16,777,216
static const size_t OFF_PART = 161480704;    // partials f32 [8192][256]    8,388,608
static const size_t OFF_S1   = 169869312;    // stage1 f32 [64][256]           65,536
static const size_t OFF_SB   = 169934848;    // scale/bias f32 [4][256]         4,096
static const size_t WS_NEED  = 169938944;

typedef __bf16 bf16x8v __attribute__((ext_vector_type(8)));
typedef float  f32x4v  __attribute__((ext_vector_type(4)));

__device__ __forceinline__ float bl(unsigned u){ return __uint_as_float(u<<16); }
__device__ __forceinline__ float bh(unsigned u){ return __uint_as_float(u & 0xffff0000u); }
__device__ __forceinline__ unsigned short bfr(float x){
  unsigned u = __float_as_uint(x);
  u += 0x7fffu + ((u>>16)&1u);
  return (unsigned short)(u>>16);
}

// ---------------- diagnostic sentinel ----------------
__global__ __launch_bounds__(256) void sentinel_kernel(float* __restrict__ out, int n, float v){
  int i = blockIdx.x*256 + threadIdx.x;
  if (i < n) out[i] = v;
}

// ---------------- transpose features (b,c,n) -> (b,n,c) ----------------
__global__ __launch_bounds__(256) void transpose_feats(const float* __restrict__ f,
                                                       float* __restrict__ ft){
  __shared__ __align__(16) float tile[64][65];
  int t = threadIdx.x;
  int b = blockIdx.x, n0 = blockIdx.y*64;
  for (int it=0; it<16; ++it){
    int flat = it*256 + t;
    int c = flat>>6, nl = flat&63;
    tile[c][nl] = f[(b*64 + c)*1024 + n0 + nl];
  }
  __syncthreads();
  for (int it=0; it<16; ++it){
    int flat = it*256 + t;
    int nl = flat>>6, c = flat&63;
    ft[((b<<10) + n0 + nl)*64 + c] = tile[c][nl];
  }
}

// ---------------- KNN: top-16 by pd = 2*inner - xx_n - xx_m, self excluded ----------------
__global__ __launch_bounds__(256) void knn_kernel(const float* __restrict__ pts,
                                                  int* __restrict__ idxout){
  __shared__ __align__(16) float px[1024], py[1024], pz[1024], xx[1024];
  int t = threadIdx.x;
  int b = blockIdx.x;
  for (int i=t; i<1024; i+=256){
    float a = pts[(b*3+0)*1024+i];
    float c = pts[(b*3+1)*1024+i];
    float d = pts[(b*3+2)*1024+i];
    px[i]=a; py[i]=c; pz[i]=d;
    xx[i] = __fadd_rn(__fadd_rn(__fmul_rn(a,a), __fmul_rn(c,c)), __fmul_rn(d,d));
  }
  __syncthreads();
  int n = blockIdx.y*256 + t;
  float qx=px[n], qy=py[n], qz=pz[n], qxx=xx[n];
  float vals[16]; int idxs[16];
  #pragma unroll
  for (int j=0;j<16;++j){ vals[j] = -3.4e38f; idxs[j] = 0; }
  for (int m=0; m<1024; ++m){
    float inner = __fadd_rn(__fadd_rn(__fmul_rn(qx,px[m]), __fmul_rn(qy,py[m])), __fmul_rn(qz,pz[m]));
    float pd = __fsub_rn(__fsub_rn(__fmul_rn(2.0f, inner), qxx), xx[m]);
    if (m != n && pd > vals[15]){
      float cv = pd; int ci = m;
      #pragma unroll
      for (int j=0;j<16;++j){
        bool take = cv > vals[j];      // strict: ties keep existing (lower index)
        float ov = vals[j]; int oi = idxs[j];
        vals[j] = take ? cv : ov;  idxs[j] = take ? ci : oi;
        cv      = take ? ov : cv;  ci      = take ? oi : ci;
      }
    }
  }
  #pragma unroll
  for (int j=0;j<16;++j) idxout[((b<<10)+n)*16 + j] = idxs[j];
}

// ---------------- MFMA GEMM: 64 rows x 128 cols per block, K=128 ----------------
// MODE 0: x gathered from featsT via knn (center || nbr-center), staged in LDS
// MODE 1: x = relu(yin*scale + bias) computed in registers from global yin (in-place safe)
// Fragment layouts (verified m89/m92): A/B lane l: 8 contiguous k at [l&15][(l>>4)*8+j];
// C/D: col = lane&15, row = (lane>>4)*4 + reg.
template<int MODE>
__global__ __launch_bounds__(256) void gemm_mfma(const float* __restrict__ featsT,
                                                 const int* __restrict__ knn,
                                                 const unsigned short* yin,
                                                 const float* __restrict__ sb,
                                                 const float* __restrict__ W,
                                                 unsigned short* yout,
                                                 float* __restrict__ partials){
  extern __shared__ char smem[];
  // mode0: [Wt 34816][xs 17408][red 4096][cen 1024][midx 256]
  // mode1: [Wt 34816 (xs aliases Wt)][red 4096][sbl 1024]
  unsigned short (*Wt)[136] = (unsigned short(*)[136])smem;
  unsigned short (*xs)[136] = (unsigned short(*)[136])(MODE==0 ? smem + 34816 : smem);
  float* red = (float*)(smem + (MODE==0 ? 52224 : 34816));       // 8*128 f32
  float* sbl = (float*)(smem + 34816 + 4096);                    // mode1 only
  float* cen = (float*)(smem + 52224 + 4096);                    // mode0 only: 4*64
  int*  midx = (int*)(smem + 52224 + 4096 + 1024);               // mode0 only: 64

  int t = threadIdx.x;
  int w = t >> 6, l = t & 63;
  int li = l & 15, lg = l >> 4;
  size_t rowbase = (size_t)blockIdx.x * 64;

  // stage W f32 -> bf16 padded LDS [o][c], stride 136
  for (int it=0; it<16; ++it){
    int vec = it*256 + t;                 // 4096 float4 vectors
    int o = vec >> 5, c4 = (vec & 31) * 4;
    float4 wv = *reinterpret_cast<const float4*>(W + o*128 + c4);
    uint2 pk;
    pk.x = (unsigned)bfr(wv.x) | ((unsigned)bfr(wv.y)<<16);
    pk.y = (unsigned)bfr(wv.z) | ((unsigned)bfr(wv.w)<<16);
    *reinterpret_cast<uint2*>(&Wt[o][c4]) = pk;
  }

  if constexpr (MODE == 0){
    int b  = (int)(rowbase >> 14);
    int n0 = (int)((rowbase >> 4) & 1023);
    if (t < 64) midx[t] = knn[rowbase + t];
    { int i = t>>6, c = t&63; cen[i*64 + c] = featsT[((b<<10) + n0 + i)*64 + c]; }
    __syncthreads();
    for (int it=0; it<16; ++it){
      int flat = it*256 + t;
      int r = flat>>6, c = flat&63;
      float cv = cen[(r>>4)*64 + c];
      float nv = featsT[(((size_t)b<<10) + midx[r])*64 + c];
      xs[r][c]    = bfr(cv);
      xs[r][64+c] = bfr(nv - cv);
    }
  } else {
    sbl[t] = sb[t];
  }
  __syncthreads();

  const unsigned short* yrow = (MODE==1) ? (yin + ((rowbase + 16*w + li) << 7) + lg*8) : nullptr;

  f32x4v acc[8] = {};
  #pragma unroll
  for (int kb=0; kb<4; ++kb){
    uint4 a4;
    if constexpr (MODE == 1){
      uint4 yv = *reinterpret_cast<const uint4*>(yrow + kb*32);
      int c0 = kb*32 + lg*8;
      float f[8];
      f[0]=bl(yv.x); f[1]=bh(yv.x); f[2]=bl(yv.y); f[3]=bh(yv.y);
      f[4]=bl(yv.z); f[5]=bh(yv.z); f[6]=bl(yv.w); f[7]=bh(yv.w);
      unsigned short p[8];
      #pragma unroll
      for (int j=0;j<8;++j){
        float v = fmaxf(fmaf(f[j], sbl[c0+j], sbl[128+c0+j]), 0.f);
        p[j] = bfr(v);
      }
      a4.x = (unsigned)p[0] | ((unsigned)p[1]<<16);
      a4.y = (unsigned)p[2] | ((unsigned)p[3]<<16);
      a4.z = (unsigned)p[4] | ((unsigned)p[5]<<16);
      a4.w = (unsigned)p[6] | ((unsigned)p[7]<<16);
    } else {
      a4 = *reinterpret_cast<const uint4*>(&xs[16*w + li][kb*32 + lg*8]);
    }
    bf16x8v av = __builtin_bit_cast(bf16x8v, a4);
    #pragma unroll
    for (int cf=0; cf<8; ++cf){
      uint4 b4 = *reinterpret_cast<const uint4*>(&Wt[cf*16 + li][kb*32 + lg*8]);
      acc[cf] = __builtin_amdgcn_mfma_f32_16x16x32_bf16(av, __builtin_bit_cast(bf16x8v, b4), acc[cf], 0, 0, 0);
    }
  }

  // per-wave BN partial stats (deterministic fixed-order)
  #pragma unroll
  for (int cf=0; cf<8; ++cf){
    float s = acc[cf][0]+acc[cf][1]+acc[cf][2]+acc[cf][3];
    s += __shfl_xor(s, 16);
    s += __shfl_xor(s, 32);
    float q = acc[cf][0]*acc[cf][0]+acc[cf][1]*acc[cf][1]+acc[cf][2]*acc[cf][2]+acc[cf][3]*acc[cf][3];
    q += __shfl_xor(q, 16);
    q += __shfl_xor(q, 32);
    if (lg == 0){
      red[w*128 + cf*16 + li]       = s;
      red[512 + w*128 + cf*16 + li] = q;
    }
  }
  __syncthreads();   // all MFMA + red writes done; xs (or aliased Wt) free for epilogue

  // scatter C frags as bf16 into LDS transpose buffer
  #pragma unroll
  for (int cf=0; cf<8; ++cf)
    #pragma unroll
    for (int r=0; r<4; ++r)
      xs[16*w + lg*4 + r][cf*16 + li] = bfr(acc[cf][r]);

  // cross-wave stats finalize: t<128 -> sums, t>=128 -> sumsq
  {
    int col = t & 127;
    int base = (t >> 7) * 512;
    float s = red[base + col] + red[base + 128 + col] + red[base + 256 + col] + red[base + 384 + col];
    partials[(size_t)blockIdx.x*256 + t] = s;
  }
  __syncthreads();

  // coalesced y store: thread t -> row t>>2, 32 cols
  {
    int row = t >> 2, q = t & 3;
    const unsigned short* src = &xs[row][q*32];
    unsigned short* dst = yout + ((rowbase + row) << 7) + q*32;
    #pragma unroll
    for (int k2=0; k2<4; ++k2)
      *reinterpret_cast<uint4*>(dst + k2*8) = *reinterpret_cast<const uint4*>(src + k2*8);
  }
}

// ---------------- shortcut GEMM: feats(64) x Wsc^T -> sc f32 ----------------
__global__ __launch_bounds__(256) void sc_gemm(const float* __restrict__ featsT,
                                               const float* __restrict__ W,
                                               float* __restrict__ scout,
                                               float* __restrict__ partials){
  __shared__ __align__(16) unsigned short Wt[64][136];
  __shared__ __align__(16) unsigned short xs[64][72];
  int t = threadIdx.x, tx = t&15, ty = t>>4;
  int rowbase = blockIdx.x * 64;
  for (int it=0; it<32; ++it){
    int flat = it*256 + t;
    int o = flat>>6, c = flat&63;
    Wt[c][o] = bfr(W[flat]);
  }
  for (int it=0; it<16; ++it){
    int flat = it*256 + t;
    int r = flat>>6, c = flat&63;
    xs[r][c] = bfr(featsT[(size_t)(rowbase + r)*64 + c]);
  }
  __syncthreads();
  float acc[4][8] = {};
  for (int c=0;c<64;++c){
    uint4 wv = *reinterpret_cast<const uint4*>(&Wt[c][tx*8]);
    float w[8];
    w[0]=bl(wv.x); w[1]=bh(wv.x); w[2]=bl(wv.y); w[3]=bh(wv.y);
    w[4]=bl(wv.z); w[5]=bh(wv.z); w[6]=bl(wv.w); w[7]=bh(wv.w);
    #pragma unroll
    for (int i=0;i<4;++i){
      float xv = bl((unsigned)xs[ty*4+i][c]);
      #pragma unroll
      for (int j=0;j<8;++j) acc[i][j] = fmaf(xv, w[j], acc[i][j]);
    }
  }
  #pragma unroll
  for (int i=0;i<4;++i)
    #pragma unroll
    for (int j=0;j<8;++j)
      scout[(size_t)(rowbase + ty*4 + i)*128 + tx*8 + j] = acc[i][j];

  __syncthreads();
  float* red = reinterpret_cast<float*>(&xs[0][0]);
  #pragma unroll
  for (int j=0;j<8;++j){
    float s=0.f;
    #pragma unroll
    for (int i=0;i<4;++i) s += acc[i][j];
    red[ty*128 + tx*8 + j] = s;
  }
  __syncthreads();
  if (t<128){
    float s=0.f;
    for (int y2=0;y2<16;++y2) s += red[y2*128 + t];
    partials[(size_t)blockIdx.x*256 + t] = s;
  }
  __syncthreads();
  #pragma unroll
  for (int j=0;j<8;++j){
    float s=0.f;
    #pragma unroll
    for (int i=0;i<4;++i) s += acc[i][j]*acc[i][j];
    red[ty*128 + tx*8 + j] = s;
  }
  __syncthreads();
  if (t<128){
    float s=0.f;
    for (int y2=0;y2<16;++y2) s += red[y2*128 + t];
    partials[(size_t)blockIdx.x*256 + 128 + t] = s;
  }
}

// ---------------- deterministic stat reduction ----------------
__global__ __launch_bounds__(256) void reduce_stage1(const float* __restrict__ partials,
                                                     float* __restrict__ out, int rows){
  int t = threadIdx.x;
  size_t base = (size_t)blockIdx.x * rows * 256;
  float acc = 0.f;
  for (int r=0;r<rows;++r) acc += partials[base + (size_t)r*256 + t];
  out[blockIdx.x*256 + t] = acc;
}

__global__ __launch_bounds__(256) void finalize_stats(const float* __restrict__ s1, int g1,
                                                      float inv_count,
                                                      const float* __restrict__ g,
                                                      const float* __restrict__ beta,
                                                      float* __restrict__ sb){
  int t = threadIdx.x;
  float acc = 0.f;
  for (int j=0;j<g1;++j) acc += s1[j*256 + t];
  __shared__ float tot[256];
  tot[t] = acc;
  __syncthreads();
  if (t < 128){
    float mean = tot[t] * inv_count;
    float var  = tot[128+t] * inv_count - mean*mean;
    var = fmaxf(var, 0.f);
    float rstd = 1.0f / sqrtf(var + 1e-5f);
    float s = g[t] * rstd;
    sb[t] = s;
    sb[128+t] = beta[t] - mean*s;
  }
}

// ---------------- final: out = relu(bn_sc(sc) + mean_k relu(bn2(y2))) , transposed ----------------
__global__ __launch_bounds__(256) void final_kernel(const unsigned short* __restrict__ y2,
                                                    const float* __restrict__ sc,
                                                    const float* __restrict__ sb2,
                                                    const float* __restrict__ sbsc,
                                                    float* __restrict__ out){
  __shared__ __align__(16) float obuf[128][66];
  int t = threadIdx.x;
  int b = blockIdx.x >> 4;
  int n0 = (blockIdx.x & 15) * 64;
  int o = t & 127, half = t >> 7;
  float s2 = sb2[o], c2 = sb2[128+o];
  float ss = sbsc[o], cs = sbsc[128+o];
  for (int nn=0; nn<64; nn+=2){
    int nl = nn + half;
    size_t row0 = ((size_t)((b<<10) + n0 + nl)) << 4;
    float acc = 0.f;
    #pragma unroll
    for (int k=0;k<16;++k){
      float v = bl((unsigned)y2[(row0 + k)*128 + o]);
      acc += fmaxf(fmaf(v, s2, c2), 0.f);
    }
    float fts = acc * (1.f/16.f);
    float scv = sc[(size_t)((b<<10) + n0 + nl)*128 + o];
    scv = fmaf(scv, ss, cs);
    obuf[o][nl] = fmaxf(scv + fts, 0.f);
  }
  __syncthreads();
  for (int it=0; it<32; ++it){
    int flat = it*256 + t;
    int oo = flat>>6, nl = flat&63;
    out[((size_t)b<<17) + (oo<<10) + n0 + nl] = obuf[oo][nl];
  }
}

extern "C" void kernel_launch(void* const* d_in, const int* in_sizes, int n_in,
                              void* d_out, int out_size, void* d_ws, size_t ws_size,
                              hipStream_t stream) {
  const float* points   = (const float*)d_in[0];
  const float* features = (const float*)d_in[1];
  const float* W0  = (const float*)d_in[2];
  const float* g0  = (const float*)d_in[3];
  const float* b0  = (const float*)d_in[4];
  const float* W1  = (const float*)d_in[5];
  const float* g1  = (const float*)d_in[6];
  const float* b1  = (const float*)d_in[7];
  const float* W2  = (const float*)d_in[8];
  const float* g2  = (const float*)d_in[9];
  const float* b2  = (const float*)d_in[10];
  const float* Wsc = (const float*)d_in[11];
  const float* gsc = (const float*)d_in[12];
  const float* bsc = (const float*)d_in[13];

  float* out = (float*)d_out;

  if (ws_size < WS_NEED){
    float v = (float)(ws_size >> 20);
    sentinel_kernel<<<(out_size + 255)/256, 256, 0, stream>>>(out, out_size, v);
    return;
  }

  char* ws = (char*)d_ws;
  float*          featsT = (float*)(ws + OFF_FT);
  int*            idx    = (int*)(ws + OFF_IDX);
  unsigned short* y      = (unsigned short*)(ws + OFF_Y);
  float*          scbuf  = (float*)(ws + OFF_SC);
  float*          part   = (float*)(ws + OFF_PART);
  float*          s1     = (float*)(ws + OFF_S1);
  float*          sb     = (float*)(ws + OFF_SB);

  transpose_feats<<<dim3(32,16), 256, 0, stream>>>(features, featsT);
  knn_kernel<<<dim3(32,4), 256, 0, stream>>>(points, idx);

  // layer 0 (gather + MFMA)
  gemm_mfma<0><<<NROW/64, 256, 57600, stream>>>(featsT, idx, nullptr, nullptr, W0, y, part);
  reduce_stage1<<<64, 256, 0, stream>>>(part, s1, 128);
  finalize_stats<<<1, 256, 0, stream>>>(s1, 64, 1.f/524288.f, g0, b0, sb + 0);
  // layer 1 (in-place MFMA)
  gemm_mfma<1><<<NROW/64, 256, 39936, stream>>>(nullptr, nullptr, y, sb + 0, W1, y, part);
  reduce_stage1<<<64, 256, 0, stream>>>(part, s1, 128);
  finalize_stats<<<1, 256, 0, stream>>>(s1, 64, 1.f/524288.f, g1, b1, sb + 256);
  // layer 2 (in-place MFMA)
  gemm_mfma<1><<<NROW/64, 256, 39936, stream>>>(nullptr, nullptr, y, sb + 256, W2, y, part);
  reduce_stage1<<<64, 256, 0, stream>>>(part, s1, 128);
  finalize_stats<<<1, 256, 0, stream>>>(s1, 64, 1.f/524288.f, g2, b2, sb + 512);
  // shortcut
  sc_gemm<<<NROWSC/64, 256, 0, stream>>>(featsT, Wsc, scbuf, part);
  reduce_stage1<<<8, 256, 0, stream>>>(part, s1, 64);
  finalize_stats<<<1, 256, 0, stream>>>(s1, 8, 1.f/32768.f, gsc, bsc, sb + 768);
  // fuse + transpose
  final_kernel<<<512, 256, 0, stream>>>(y, scbuf, sb + 512, sb + 768, out);
}

// Round 4
// 764.757 us; speedup vs baseline: 1.6484x; 1.1036x over previous
//
#include <hip/hip_runtime.h>

// EdgeConvBlock: B=32, N=1024, D=3, CIN=64, K=16, COUT=128x3
// Round 4: chunk-parallel KNN (4 waves/query-group, 512 blocks) + stable 4-way merge.

#define BB 32
#define NN 1024
#define CINC 64
#define KK 16
#define CO 128
#define NROW (BB*NN*KK)   // 524288
#define NROWSC (BB*NN)    // 32768

// ---- ws layout (bytes) ----
static const size_t OFF_FT   = 0;            // featsT f32 [B][N][64]       8,388,608
static const size_t OFF_IDX  = 8388608;      // idx int  [B][N][16]         2,097,152
static const size_t OFF_Y    = 10485760;     // y  bf16  [NROW][128]      134,217,728
static const size_t OFF_SC   = 144703488;    // sc f32   [NROWSC][128]     16,777,216
static const size_t OFF_PART = 161480704;    // partials f32 [8192][256]    8,388,608
static const size_t OFF_S1   = 169869312;    // stage1 f32 [64][256]           65,536
static const size_t OFF_SB   = 169934848;    // scale/bias f32 [4][256]         4,096
static const size_t WS_NEED  = 169938944;

typedef __bf16 bf16x8v __attribute__((ext_vector_type(8)));
typedef float  f32x4v  __attribute__((ext_vector_type(4)));

__device__ __forceinline__ float bl(unsigned u){ return __uint_as_float(u<<16); }
__device__ __forceinline__ float bh(unsigned u){ return __uint_as_float(u & 0xffff0000u); }
__device__ __forceinline__ unsigned short bfr(float x){
  unsigned u = __float_as_uint(x);
  u += 0x7fffu + ((u>>16)&1u);
  return (unsigned short)(u>>16);
}

// ---------------- diagnostic sentinel ----------------
__global__ __launch_bounds__(256) void sentinel_kernel(float* __restrict__ out, int n, float v){
  int i = blockIdx.x*256 + threadIdx.x;
  if (i < n) out[i] = v;
}

// ---------------- transpose features (b,c,n) -> (b,n,c) ----------------
__global__ __launch_bounds__(256) void transpose_feats(const float* __restrict__ f,
                                                       float* __restrict__ ft){
  __shared__ __align__(16) float tile[64][65];
  int t = threadIdx.x;
  int b = blockIdx.x, n0 = blockIdx.y*64;
  for (int it=0; it<16; ++it){
    int flat = it*256 + t;
    int c = flat>>6, nl = flat&63;
    tile[c][nl] = f[(b*64 + c)*1024 + n0 + nl];
  }
  __syncthreads();
  for (int it=0; it<16; ++it){
    int flat = it*256 + t;
    int nl = flat>>6, c = flat&63;
    ft[((b<<10) + n0 + nl)*64 + c] = tile[c][nl];
  }
}

// ---------------- KNN v2: chunk-parallel top-16 ----------------
// Block (b, g): queries n in [g*64, g*64+64), 4 chunks of 256 candidates.
// thread t: chunk c = t>>6 (wave-uniform), lane l = t&63, query n = g*64+l.
// Stable: within-chunk strict-> insertion keeps earliest m; merge prefers
// lowest chunk on ties -> exact lax.top_k order.
__global__ __launch_bounds__(256) void knn_kernel(const float* __restrict__ pts,
                                                  int* __restrict__ idxout){
  __shared__ __align__(16) float px[1024], py[1024], pz[1024], xx[1024];
  __shared__ float mv[4][64][17];
  __shared__ int   mi[4][64][17];
  int t = threadIdx.x;
  int b = blockIdx.x, g = blockIdx.y;
  for (int i=t; i<1024; i+=256){
    float a = pts[(b*3+0)*1024+i];
    float c = pts[(b*3+1)*1024+i];
    float d = pts[(b*3+2)*1024+i];
    px[i]=a; py[i]=c; pz[i]=d;
    xx[i] = __fadd_rn(__fadd_rn(__fmul_rn(a,a), __fmul_rn(c,c)), __fmul_rn(d,d));
  }
  __syncthreads();
  int c = t >> 6, l = t & 63;
  int n = g*64 + l;
  float qx=px[n], qy=py[n], qz=pz[n], qxx=xx[n];
  float vals[16]; int idxs[16];
  #pragma unroll
  for (int j=0;j<16;++j){ vals[j] = -3.4e38f; idxs[j] = 0; }
  int m0 = c*256;
  for (int m=m0; m<m0+256; ++m){
    // match np: mul+add (no fma), then (2*inner - xx_n) - xx_m
    float inner = __fadd_rn(__fadd_rn(__fmul_rn(qx,px[m]), __fmul_rn(qy,py[m])), __fmul_rn(qz,pz[m]));
    float pd = __fsub_rn(__fsub_rn(__fmul_rn(2.0f, inner), qxx), xx[m]);
    if (m != n && pd > vals[15]){
      float cv = pd; int ci = m;
      #pragma unroll
      for (int j=0;j<16;++j){
        bool take = cv > vals[j];      // strict: ties keep existing (lower index)
        float ov = vals[j]; int oi = idxs[j];
        vals[j] = take ? cv : ov;  idxs[j] = take ? ci : oi;
        cv      = take ? ov : cv;  ci      = take ? oi : ci;
      }
    }
  }
  #pragma unroll
  for (int j=0;j<16;++j){ mv[c][l][j] = vals[j]; mi[c][l][j] = idxs[j]; }
  __syncthreads();
  if (t < 64){
    int p0=0,p1=0,p2=0,p3=0;
    int* dst = idxout + ((size_t)((b<<10) + g*64 + t))*16;
    #pragma unroll
    for (int j=0;j<16;++j){
      float v0 = mv[0][t][p0], v1 = mv[1][t][p1], v2 = mv[2][t][p2], v3 = mv[3][t][p3];
      float best = v0; int bc = 0;
      if (v1 > best){ best = v1; bc = 1; }   // strict: ties keep lower chunk (lower m)
      if (v2 > best){ best = v2; bc = 2; }
      if (v3 > best){ best = v3; bc = 3; }
      int oi;
      if      (bc==0){ oi = mi[0][t][p0]; ++p0; }
      else if (bc==1){ oi = mi[1][t][p1]; ++p1; }
      else if (bc==2){ oi = mi[2][t][p2]; ++p2; }
      else           { oi = mi[3][t][p3]; ++p3; }
      dst[j] = oi;
    }
  }
}

// ---------------- MFMA GEMM: 64 rows x 128 cols per block, K=128 ----------------
// MODE 0: x gathered from featsT via knn (center || nbr-center), staged in LDS
// MODE 1: x = relu(yin*scale + bias) computed in registers from global yin (in-place safe)
// Fragment layouts (verified m89/m92): A/B lane l: 8 contiguous k at [l&15][(l>>4)*8+j];
// C/D: col = lane&15, row = (lane>>4)*4 + reg.
template<int MODE>
__global__ __launch_bounds__(256) void gemm_mfma(const float* __restrict__ featsT,
                                                 const int* __restrict__ knn,
                                                 const unsigned short* yin,
                                                 const float* __restrict__ sb,
                                                 const float* __restrict__ W,
                                                 unsigned short* yout,
                                                 float* __restrict__ partials){
  extern __shared__ char smem[];
  // mode0: [Wt 34816][xs 17408][red 4096][cen 1024][midx 256]
  // mode1: [Wt 34816 (xs aliases Wt)][red 4096][sbl 1024]
  unsigned short (*Wt)[136] = (unsigned short(*)[136])smem;
  unsigned short (*xs)[136] = (unsigned short(*)[136])(MODE==0 ? smem + 34816 : smem);
  float* red = (float*)(smem + (MODE==0 ? 52224 : 34816));       // 8*128 f32
  float* sbl = (float*)(smem + 34816 + 4096);                    // mode1 only
  float* cen = (float*)(smem + 52224 + 4096);                    // mode0 only: 4*64
  int*  midx = (int*)(smem + 52224 + 4096 + 1024);               // mode0 only: 64

  int t = threadIdx.x;
  int w = t >> 6, l = t & 63;
  int li = l & 15, lg = l >> 4;
  size_t rowbase = (size_t)blockIdx.x * 64;

  // stage W f32 -> bf16 padded LDS [o][c], stride 136
  for (int it=0; it<16; ++it){
    int vec = it*256 + t;                 // 4096 float4 vectors
    int o = vec >> 5, c4 = (vec & 31) * 4;
    float4 wv = *reinterpret_cast<const float4*>(W + o*128 + c4);
    uint2 pk;
    pk.x = (unsigned)bfr(wv.x) | ((unsigned)bfr(wv.y)<<16);
    pk.y = (unsigned)bfr(wv.z) | ((unsigned)bfr(wv.w)<<16);
    *reinterpret_cast<uint2*>(&Wt[o][c4]) = pk;
  }

  if constexpr (MODE == 0){
    int b  = (int)(rowbase >> 14);
    int n0 = (int)((rowbase >> 4) & 1023);
    if (t < 64) midx[t] = knn[rowbase + t];
    { int i = t>>6, c = t&63; cen[i*64 + c] = featsT[((b<<10) + n0 + i)*64 + c]; }
    __syncthreads();
    for (int it=0; it<16; ++it){
      int flat = it*256 + t;
      int r = flat>>6, c = flat&63;
      float cv = cen[(r>>4)*64 + c];
      float nv = featsT[(((size_t)b<<10) + midx[r])*64 + c];
      xs[r][c]    = bfr(cv);
      xs[r][64+c] = bfr(nv - cv);
    }
  } else {
    sbl[t] = sb[t];
  }
  __syncthreads();

  const unsigned short* yrow = (MODE==1) ? (yin + ((rowbase + 16*w + li) << 7) + lg*8) : nullptr;

  f32x4v acc[8] = {};
  #pragma unroll
  for (int kb=0; kb<4; ++kb){
    uint4 a4;
    if constexpr (MODE == 1){
      uint4 yv = *reinterpret_cast<const uint4*>(yrow + kb*32);
      int c0 = kb*32 + lg*8;
      float f[8];
      f[0]=bl(yv.x); f[1]=bh(yv.x); f[2]=bl(yv.y); f[3]=bh(yv.y);
      f[4]=bl(yv.z); f[5]=bh(yv.z); f[6]=bl(yv.w); f[7]=bh(yv.w);
      unsigned short p[8];
      #pragma unroll
      for (int j=0;j<8;++j){
        float v = fmaxf(fmaf(f[j], sbl[c0+j], sbl[128+c0+j]), 0.f);
        p[j] = bfr(v);
      }
      a4.x = (unsigned)p[0] | ((unsigned)p[1]<<16);
      a4.y = (unsigned)p[2] | ((unsigned)p[3]<<16);
      a4.z = (unsigned)p[4] | ((unsigned)p[5]<<16);
      a4.w = (unsigned)p[6] | ((unsigned)p[7]<<16);
    } else {
      a4 = *reinterpret_cast<const uint4*>(&xs[16*w + li][kb*32 + lg*8]);
    }
    bf16x8v av = __builtin_bit_cast(bf16x8v, a4);
    #pragma unroll
    for (int cf=0; cf<8; ++cf){
      uint4 b4 = *reinterpret_cast<const uint4*>(&Wt[cf*16 + li][kb*32 + lg*8]);
      acc[cf] = __builtin_amdgcn_mfma_f32_16x16x32_bf16(av, __builtin_bit_cast(bf16x8v, b4), acc[cf], 0, 0, 0);
    }
  }

  // per-wave BN partial stats (deterministic fixed-order)
  #pragma unroll
  for (int cf=0; cf<8; ++cf){
    float s = acc[cf][0]+acc[cf][1]+acc[cf][2]+acc[cf][3];
    s += __shfl_xor(s, 16);
    s += __shfl_xor(s, 32);
    float q = acc[cf][0]*acc[cf][0]+acc[cf][1]*acc[cf][1]+acc[cf][2]*acc[cf][2]+acc[cf][3]*acc[cf][3];
    q += __shfl_xor(q, 16);
    q += __shfl_xor(q, 32);
    if (lg == 0){
      red[w*128 + cf*16 + li]       = s;
      red[512 + w*128 + cf*16 + li] = q;
    }
  }
  __syncthreads();   // all MFMA + red writes done; xs (or aliased Wt) free for epilogue

  // scatter C frags as bf16 into LDS transpose buffer
  #pragma unroll
  for (int cf=0; cf<8; ++cf)
    #pragma unroll
    for (int r=0; r<4; ++r)
      xs[16*w + lg*4 + r][cf*16 + li] = bfr(acc[cf][r]);

  // cross-wave stats finalize: t<128 -> sums, t>=128 -> sumsq
  {
    int col = t & 127;
    int base = (t >> 7) * 512;
    float s = red[base + col] + red[base + 128 + col] + red[base + 256 + col] + red[base + 384 + col];
    partials[(size_t)blockIdx.x*256 + t] = s;
  }
  __syncthreads();

  // coalesced y store: thread t -> row t>>2, 32 cols
  {
    int row = t >> 2, q = t & 3;
    const unsigned short* src = &xs[row][q*32];
    unsigned short* dst = yout + ((rowbase + row) << 7) + q*32;
    #pragma unroll
    for (int k2=0; k2<4; ++k2)
      *reinterpret_cast<uint4*>(dst + k2*8) = *reinterpret_cast<const uint4*>(src + k2*8);
  }
}

// ---------------- shortcut GEMM: feats(64) x Wsc^T -> sc f32 ----------------
__global__ __launch_bounds__(256) void sc_gemm(const float* __restrict__ featsT,
                                               const float* __restrict__ W,
                                               float* __restrict__ scout,
                                               float* __restrict__ partials){
  __shared__ __align__(16) unsigned short Wt[64][136];
  __shared__ __align__(16) unsigned short xs[64][72];
  int t = threadIdx.x, tx = t&15, ty = t>>4;
  int rowbase = blockIdx.x * 64;
  for (int it=0; it<32; ++it){
    int flat = it*256 + t;
    int o = flat>>6, c = flat&63;
    Wt[c][o] = bfr(W[flat]);
  }
  for (int it=0; it<16; ++it){
    int flat = it*256 + t;
    int r = flat>>6, c = flat&63;
    xs[r][c] = bfr(featsT[(size_t)(rowbase + r)*64 + c]);
  }
  __syncthreads();
  float acc[4][8] = {};
  for (int c=0;c<64;++c){
    uint4 wv = *reinterpret_cast<const uint4*>(&Wt[c][tx*8]);
    float w[8];
    w[0]=bl(wv.x); w[1]=bh(wv.x); w[2]=bl(wv.y); w[3]=bh(wv.y);
    w[4]=bl(wv.z); w[5]=bh(wv.z); w[6]=bl(wv.w); w[7]=bh(wv.w);
    #pragma unroll
    for (int i=0;i<4;++i){
      float xv = bl((unsigned)xs[ty*4+i][c]);
      #pragma unroll
      for (int j=0;j<8;++j) acc[i][j] = fmaf(xv, w[j], acc[i][j]);
    }
  }
  #pragma unroll
  for (int i=0;i<4;++i)
    #pragma unroll
    for (int j=0;j<8;++j)
      scout[(size_t)(rowbase + ty*4 + i)*128 + tx*8 + j] = acc[i][j];

  __syncthreads();
  float* red = reinterpret_cast<float*>(&xs[0][0]);
  #pragma unroll
  for (int j=0;j<8;++j){
    float s=0.f;
    #pragma unroll
    for (int i=0;i<4;++i) s += acc[i][j];
    red[ty*128 + tx*8 + j] = s;
  }
  __syncthreads();
  if (t<128){
    float s=0.f;
    for (int y2=0;y2<16;++y2) s += red[y2*128 + t];
    partials[(size_t)blockIdx.x*256 + t] = s;
  }
  __syncthreads();
  #pragma unroll
  for (int j=0;j<8;++j){
    float s=0.f;
    #pragma unroll
    for (int i=0;i<4;++i) s += acc[i][j]*acc[i][j];
    red[ty*128 + tx*8 + j] = s;
  }
  __syncthreads();
  if (t<128){
    float s=0.f;
    for (int y2=0;y2<16;++y2) s += red[y2*128 + t];
    partials[(size_t)blockIdx.x*256 + 128 + t] = s;
  }
}

// ---------------- deterministic stat reduction ----------------
__global__ __launch_bounds__(256) void reduce_stage1(const float* __restrict__ partials,
                                                     float* __restrict__ out, int rows){
  int t = threadIdx.x;
  size_t base = (size_t)blockIdx.x * rows * 256;
  float acc = 0.f;
  for (int r=0;r<rows;++r) acc += partials[base + (size_t)r*256 + t];
  out[blockIdx.x*256 + t] = acc;
}

__global__ __launch_bounds__(256) void finalize_stats(const float* __restrict__ s1, int g1,
                                                      float inv_count,
                                                      const float* __restrict__ g,
                                                      const float* __restrict__ beta,
                                                      float* __restrict__ sb){
  int t = threadIdx.x;
  float acc = 0.f;
  for (int j=0;j<g1;++j) acc += s1[j*256 + t];
  __shared__ float tot[256];
  tot[t] = acc;
  __syncthreads();
  if (t < 128){
    float mean = tot[t] * inv_count;
    float var  = tot[128+t] * inv_count - mean*mean;
    var = fmaxf(var, 0.f);
    float rstd = 1.0f / sqrtf(var + 1e-5f);
    float s = g[t] * rstd;
    sb[t] = s;
    sb[128+t] = beta[t] - mean*s;
  }
}

// ---------------- final: out = relu(bn_sc(sc) + mean_k relu(bn2(y2))) , transposed ----------------
__global__ __launch_bounds__(256) void final_kernel(const unsigned short* __restrict__ y2,
                                                    const float* __restrict__ sc,
                                                    const float* __restrict__ sb2,
                                                    const float* __restrict__ sbsc,
                                                    float* __restrict__ out){
  __shared__ __align__(16) float obuf[128][66];
  int t = threadIdx.x;
  int b = blockIdx.x >> 4;
  int n0 = (blockIdx.x & 15) * 64;
  int o = t & 127, half = t >> 7;
  float s2 = sb2[o], c2 = sb2[128+o];
  float ss = sbsc[o], cs = sbsc[128+o];
  for (int nn=0; nn<64; nn+=2){
    int nl = nn + half;
    size_t row0 = ((size_t)((b<<10) + n0 + nl)) << 4;
    float acc = 0.f;
    #pragma unroll
    for (int k=0;k<16;++k){
      float v = bl((unsigned)y2[(row0 + k)*128 + o]);
      acc += fmaxf(fmaf(v, s2, c2), 0.f);
    }
    float fts = acc * (1.f/16.f);
    float scv = sc[(size_t)((b<<10) + n0 + nl)*128 + o];
    scv = fmaf(scv, ss, cs);
    obuf[o][nl] = fmaxf(scv + fts, 0.f);
  }
  __syncthreads();
  for (int it=0; it<32; ++it){
    int flat = it*256 + t;
    int oo = flat>>6, nl = flat&63;
    out[((size_t)b<<17) + (oo<<10) + n0 + nl] = obuf[oo][nl];
  }
}

extern "C" void kernel_launch(void* const* d_in, const int* in_sizes, int n_in,
                              void* d_out, int out_size, void* d_ws, size_t ws_size,
                              hipStream_t stream) {
  const float* points   = (const float*)d_in[0];
  const float* features = (const float*)d_in[1];
  const float* W0  = (const float*)d_in[2];
  const float* g0  = (const float*)d_in[3];
  const float* b0  = (const float*)d_in[4];
  const float* W1  = (const float*)d_in[5];
  const float* g1  = (const float*)d_in[6];
  const float* b1  = (const float*)d_in[7];
  const float* W2  = (const float*)d_in[8];
  const float* g2  = (const float*)d_in[9];
  const float* b2  = (const float*)d_in[10];
  const float* Wsc = (const float*)d_in[11];
  const float* gsc = (const float*)d_in[12];
  const float* bsc = (const float*)d_in[13];

  float* out = (float*)d_out;

  if (ws_size < WS_NEED){
    float v = (float)(ws_size >> 20);
    sentinel_kernel<<<(out_size + 255)/256, 256, 0, stream>>>(out, out_size, v);
    return;
  }

  char* ws = (char*)d_ws;
  float*          featsT = (float*)(ws + OFF_FT);
  int*            idx    = (int*)(ws + OFF_IDX);
  unsigned short* y      = (unsigned short*)(ws + OFF_Y);
  float*          scbuf  = (float*)(ws + OFF_SC);
  float*          part   = (float*)(ws + OFF_PART);
  float*          s1     = (float*)(ws + OFF_S1);
  float*          sb     = (float*)(ws + OFF_SB);

  transpose_feats<<<dim3(32,16), 256, 0, stream>>>(features, featsT);
  knn_kernel<<<dim3(32,16), 256, 0, stream>>>(points, idx);

  // layer 0 (gather + MFMA)
  gemm_mfma<0><<<NROW/64, 256, 57600, stream>>>(featsT, idx, nullptr, nullptr, W0, y, part);
  reduce_stage1<<<64, 256, 0, stream>>>(part, s1, 128);
  finalize_stats<<<1, 256, 0, stream>>>(s1, 64, 1.f/524288.f, g0, b0, sb + 0);
  // layer 1 (in-place MFMA)
  gemm_mfma<1><<<NROW/64, 256, 39936, stream>>>(nullptr, nullptr, y, sb + 0, W1, y, part);
  reduce_stage1<<<64, 256, 0, stream>>>(part, s1, 128);
  finalize_stats<<<1, 256, 0, stream>>>(s1, 64, 1.f/524288.f, g1, b1, sb + 256);
  // layer 2 (in-place MFMA)
  gemm_mfma<1><<<NROW/64, 256, 39936, stream>>>(nullptr, nullptr, y, sb + 256, W2, y, part);
  reduce_stage1<<<64, 256, 0, stream>>>(part, s1, 128);
  finalize_stats<<<1, 256, 0, stream>>>(s1, 64, 1.f/524288.f, g2, b2, sb + 512);
  // shortcut
  sc_gemm<<<NROWSC/64, 256, 0, stream>>>(featsT, Wsc, scbuf, part);
  reduce_stage1<<<8, 256, 0, stream>>>(part, s1, 64);
  finalize_stats<<<1, 256, 0, stream>>>(s1, 8, 1.f/32768.f, gsc, bsc, sb + 768);
  // fuse + transpose
  final_kernel<<<512, 256, 0, stream>>>(y, scbuf, sb + 512, sb + 768, out);
}

// Round 5
// 708.631 us; speedup vs baseline: 1.7789x; 1.0792x over previous
//
#include <hip/hip_runtime.h>

// EdgeConvBlock: B=32, N=1024, D=3, CIN=64, K=16, COUT=128x3
// Round 5: KNN occupancy/latency fix — 1024 blocks, float4 points, LDS aliasing,
//          4-wide candidate tiles, 8-way stable merge.

#define BB 32
#define NN 1024
#define CINC 64
#define KK 16
#define CO 128
#define NROW (BB*NN*KK)   // 524288
#define NROWSC (BB*NN)    // 32768

// ---- ws layout (bytes) ----
static const size_t OFF_FT   = 0;            // featsT f32 [B][N][64]       8,388,608
static const size_t OFF_IDX  = 8388608;      // idx int  [B][N][16]         2,097,152
static const size_t OFF_Y    = 10485760;     // y  bf16  [NROW][128]      134,217,728
static const size_t OFF_SC   = 144703488;    // sc f32   [NROWSC][128]     16,777,216
static const size_t OFF_PART = 161480704;    // partials f32 [8192][256]    8,388,608
static const size_t OFF_S1   = 169869312;    // stage1 f32 [64][256]           65,536
static const size_t OFF_SB   = 169934848;    // scale/bias f32 [4][256]         4,096
static const size_t WS_NEED  = 169938944;

typedef __bf16 bf16x8v __attribute__((ext_vector_type(8)));
typedef float  f32x4v  __attribute__((ext_vector_type(4)));

__device__ __forceinline__ float bl(unsigned u){ return __uint_as_float(u<<16); }
__device__ __forceinline__ float bh(unsigned u){ return __uint_as_float(u & 0xffff0000u); }
__device__ __forceinline__ unsigned short bfr(float x){
  unsigned u = __float_as_uint(x);
  u += 0x7fffu + ((u>>16)&1u);
  return (unsigned short)(u>>16);
}

// ---------------- diagnostic sentinel ----------------
__global__ __launch_bounds__(256) void sentinel_kernel(float* __restrict__ out, int n, float v){
  int i = blockIdx.x*256 + threadIdx.x;
  if (i < n) out[i] = v;
}

// ---------------- transpose features (b,c,n) -> (b,n,c) ----------------
__global__ __launch_bounds__(256) void transpose_feats(const float* __restrict__ f,
                                                       float* __restrict__ ft){
  __shared__ __align__(16) float tile[64][65];
  int t = threadIdx.x;
  int b = blockIdx.x, n0 = blockIdx.y*64;
  for (int it=0; it<16; ++it){
    int flat = it*256 + t;
    int c = flat>>6, nl = flat&63;
    tile[c][nl] = f[(b*64 + c)*1024 + n0 + nl];
  }
  __syncthreads();
  for (int it=0; it<16; ++it){
    int flat = it*256 + t;
    int nl = flat>>6, c = flat&63;
    ft[((b<<10) + n0 + nl)*64 + c] = tile[c][nl];
  }
}

// ---------------- KNN v3: 32 queries x 8 chunks of 128 per block ----------------
// Stable = exact lax.top_k order: within-chunk strict-> insertion keeps earliest m;
// chunks are ascending-m blocks; merge prefers lowest chunk on ties.
// LDS: points float4[1024] (16KB) aliased with merge lists (34.8KB) -> 4 blocks/CU.
__global__ __launch_bounds__(256) void knn_kernel(const float* __restrict__ pts,
                                                  int* __restrict__ idxout){
  __shared__ __align__(16) char smem[34816];
  float4* p4 = (float4*)smem;                         // [1024] during scan
  float (*mvv)[32][17] = (float(*)[32][17])smem;      // [8][32][17] after scan
  int   (*mii)[32][17] = (int(*)[32][17])(smem + 17408);

  int t = threadIdx.x;
  int b = blockIdx.x, g = blockIdx.y;
  for (int i=t; i<1024; i+=256){
    float a = pts[(b*3+0)*1024+i];
    float c = pts[(b*3+1)*1024+i];
    float d = pts[(b*3+2)*1024+i];
    float xx = __fadd_rn(__fadd_rn(__fmul_rn(a,a), __fmul_rn(c,c)), __fmul_rn(d,d));
    p4[i] = make_float4(a, c, d, xx);
  }
  __syncthreads();

  int q = t & 31, c = t >> 5;       // query-in-block, chunk
  int n = g*32 + q;
  float4 qp = p4[n];
  float qx=qp.x, qy=qp.y, qz=qp.z, qxx=qp.w;
  float vals[16]; int idxs[16];
  #pragma unroll
  for (int j=0;j<16;++j){ vals[j] = -3.4e38f; idxs[j] = 0; }

  int m0 = c*128;
  for (int i0=0; i0<128; i0+=4){
    float4 cand[4];
    #pragma unroll
    for (int u=0;u<4;++u) cand[u] = p4[m0 + i0 + u];
    #pragma unroll
    for (int u=0;u<4;++u){
      int m = m0 + i0 + u;
      // match np: mul+add (no fma), then (2*inner - xx_n) - xx_m
      float inner = __fadd_rn(__fadd_rn(__fmul_rn(qx,cand[u].x), __fmul_rn(qy,cand[u].y)), __fmul_rn(qz,cand[u].z));
      float pd = __fsub_rn(__fsub_rn(__fmul_rn(2.0f, inner), qxx), cand[u].w);
      if (m != n && pd > vals[15]){
        float cv = pd; int ci = m;
        #pragma unroll
        for (int j=0;j<16;++j){
          bool take = cv > vals[j];    // strict: ties keep existing (lower index)
          float ov = vals[j]; int oi = idxs[j];
          vals[j] = take ? cv : ov;  idxs[j] = take ? ci : oi;
          cv      = take ? ov : cv;  ci      = take ? oi : ci;
        }
      }
    }
  }
  __syncthreads();                    // all scans done; points dead -> lists live
  #pragma unroll
  for (int j=0;j<16;++j){ mvv[c][q][j] = vals[j]; mii[c][q][j] = idxs[j]; }
  mvv[c][q][16] = -3.4e38f; mii[c][q][16] = 0;   // sentinel guards pointer overrun
  __syncthreads();

  if (t < 32){
    int qq = t;
    int p0=0,p1=0,p2=0,p3=0,p4i=0,p5=0,p6=0,p7=0;
    float v0=mvv[0][qq][0], v1=mvv[1][qq][0], v2=mvv[2][qq][0], v3=mvv[3][qq][0];
    float v4=mvv[4][qq][0], v5=mvv[5][qq][0], v6=mvv[6][qq][0], v7=mvv[7][qq][0];
    int* dst = idxout + ((size_t)((b<<10) + g*32 + qq))*16;
    #pragma unroll
    for (int j=0;j<16;++j){
      float best = v0; int bc = 0;
      if (v1 > best){ best = v1; bc = 1; }   // strict: ties keep lower chunk (lower m)
      if (v2 > best){ best = v2; bc = 2; }
      if (v3 > best){ best = v3; bc = 3; }
      if (v4 > best){ best = v4; bc = 4; }
      if (v5 > best){ best = v5; bc = 5; }
      if (v6 > best){ best = v6; bc = 6; }
      if (v7 > best){ best = v7; bc = 7; }
      int oi;
      if      (bc==0){ oi = mii[0][qq][p0]; ++p0; v0 = mvv[0][qq][p0]; }
      else if (bc==1){ oi = mii[1][qq][p1]; ++p1; v1 = mvv[1][qq][p1]; }
      else if (bc==2){ oi = mii[2][qq][p2]; ++p2; v2 = mvv[2][qq][p2]; }
      else if (bc==3){ oi = mii[3][qq][p3]; ++p3; v3 = mvv[3][qq][p3]; }
      else if (bc==4){ oi = mii[4][qq][p4i]; ++p4i; v4 = mvv[4][qq][p4i]; }
      else if (bc==5){ oi = mii[5][qq][p5]; ++p5; v5 = mvv[5][qq][p5]; }
      else if (bc==6){ oi = mii[6][qq][p6]; ++p6; v6 = mvv[6][qq][p6]; }
      else           { oi = mii[7][qq][p7]; ++p7; v7 = mvv[7][qq][p7]; }
      dst[j] = oi;
    }
  }
}

// ---------------- MFMA GEMM: 64 rows x 128 cols per block, K=128 ----------------
// MODE 0: x gathered from featsT via knn (center || nbr-center), staged in LDS
// MODE 1: x = relu(yin*scale + bias) computed in registers from global yin (in-place safe)
// Fragment layouts (verified m89/m92): A/B lane l: 8 contiguous k at [l&15][(l>>4)*8+j];
// C/D: col = lane&15, row = (lane>>4)*4 + reg.
template<int MODE>
__global__ __launch_bounds__(256) void gemm_mfma(const float* __restrict__ featsT,
                                                 const int* __restrict__ knn,
                                                 const unsigned short* yin,
                                                 const float* __restrict__ sb,
                                                 const float* __restrict__ W,
                                                 unsigned short* yout,
                                                 float* __restrict__ partials){
  extern __shared__ char smem[];
  // mode0: [Wt 34816][xs 17408][red 4096][cen 1024][midx 256]
  // mode1: [Wt 34816 (xs aliases Wt)][red 4096][sbl 1024]
  unsigned short (*Wt)[136] = (unsigned short(*)[136])smem;
  unsigned short (*xs)[136] = (unsigned short(*)[136])(MODE==0 ? smem + 34816 : smem);
  float* red = (float*)(smem + (MODE==0 ? 52224 : 34816));       // 8*128 f32
  float* sbl = (float*)(smem + 34816 + 4096);                    // mode1 only
  float* cen = (float*)(smem + 52224 + 4096);                    // mode0 only: 4*64
  int*  midx = (int*)(smem + 52224 + 4096 + 1024);               // mode0 only: 64

  int t = threadIdx.x;
  int w = t >> 6, l = t & 63;
  int li = l & 15, lg = l >> 4;
  size_t rowbase = (size_t)blockIdx.x * 64;

  // stage W f32 -> bf16 padded LDS [o][c], stride 136
  for (int it=0; it<16; ++it){
    int vec = it*256 + t;                 // 4096 float4 vectors
    int o = vec >> 5, c4 = (vec & 31) * 4;
    float4 wv = *reinterpret_cast<const float4*>(W + o*128 + c4);
    uint2 pk;
    pk.x = (unsigned)bfr(wv.x) | ((unsigned)bfr(wv.y)<<16);
    pk.y = (unsigned)bfr(wv.z) | ((unsigned)bfr(wv.w)<<16);
    *reinterpret_cast<uint2*>(&Wt[o][c4]) = pk;
  }

  if constexpr (MODE == 0){
    int b  = (int)(rowbase >> 14);
    int n0 = (int)((rowbase >> 4) & 1023);
    if (t < 64) midx[t] = knn[rowbase + t];
    { int i = t>>6, c = t&63; cen[i*64 + c] = featsT[((b<<10) + n0 + i)*64 + c]; }
    __syncthreads();
    for (int it=0; it<16; ++it){
      int flat = it*256 + t;
      int r = flat>>6, c = flat&63;
      float cv = cen[(r>>4)*64 + c];
      float nv = featsT[(((size_t)b<<10) + midx[r])*64 + c];
      xs[r][c]    = bfr(cv);
      xs[r][64+c] = bfr(nv - cv);
    }
  } else {
    sbl[t] = sb[t];
  }
  __syncthreads();

  const unsigned short* yrow = (MODE==1) ? (yin + ((rowbase + 16*w + li) << 7) + lg*8) : nullptr;

  f32x4v acc[8] = {};
  #pragma unroll
  for (int kb=0; kb<4; ++kb){
    uint4 a4;
    if constexpr (MODE == 1){
      uint4 yv = *reinterpret_cast<const uint4*>(yrow + kb*32);
      int c0 = kb*32 + lg*8;
      float f[8];
      f[0]=bl(yv.x); f[1]=bh(yv.x); f[2]=bl(yv.y); f[3]=bh(yv.y);
      f[4]=bl(yv.z); f[5]=bh(yv.z); f[6]=bl(yv.w); f[7]=bh(yv.w);
      unsigned short p[8];
      #pragma unroll
      for (int j=0;j<8;++j){
        float v = fmaxf(fmaf(f[j], sbl[c0+j], sbl[128+c0+j]), 0.f);
        p[j] = bfr(v);
      }
      a4.x = (unsigned)p[0] | ((unsigned)p[1]<<16);
      a4.y = (unsigned)p[2] | ((unsigned)p[3]<<16);
      a4.z = (unsigned)p[4] | ((unsigned)p[5]<<16);
      a4.w = (unsigned)p[6] | ((unsigned)p[7]<<16);
    } else {
      a4 = *reinterpret_cast<const uint4*>(&xs[16*w + li][kb*32 + lg*8]);
    }
    bf16x8v av = __builtin_bit_cast(bf16x8v, a4);
    #pragma unroll
    for (int cf=0; cf<8; ++cf){
      uint4 b4 = *reinterpret_cast<const uint4*>(&Wt[cf*16 + li][kb*32 + lg*8]);
      acc[cf] = __builtin_amdgcn_mfma_f32_16x16x32_bf16(av, __builtin_bit_cast(bf16x8v, b4), acc[cf], 0, 0, 0);
    }
  }

  // per-wave BN partial stats (deterministic fixed-order)
  #pragma unroll
  for (int cf=0; cf<8; ++cf){
    float s = acc[cf][0]+acc[cf][1]+acc[cf][2]+acc[cf][3];
    s += __shfl_xor(s, 16);
    s += __shfl_xor(s, 32);
    float q = acc[cf][0]*acc[cf][0]+acc[cf][1]*acc[cf][1]+acc[cf][2]*acc[cf][2]+acc[cf][3]*acc[cf][3];
    q += __shfl_xor(q, 16);
    q += __shfl_xor(q, 32);
    if (lg == 0){
      red[w*128 + cf*16 + li]       = s;
      red[512 + w*128 + cf*16 + li] = q;
    }
  }
  __syncthreads();   // all MFMA + red writes done; xs (or aliased Wt) free for epilogue

  // scatter C frags as bf16 into LDS transpose buffer
  #pragma unroll
  for (int cf=0; cf<8; ++cf)
    #pragma unroll
    for (int r=0; r<4; ++r)
      xs[16*w + lg*4 + r][cf*16 + li] = bfr(acc[cf][r]);

  // cross-wave stats finalize: t<128 -> sums, t>=128 -> sumsq
  {
    int col = t & 127;
    int base = (t >> 7) * 512;
    float s = red[base + col] + red[base + 128 + col] + red[base + 256 + col] + red[base + 384 + col];
    partials[(size_t)blockIdx.x*256 + t] = s;
  }
  __syncthreads();

  // coalesced y store: thread t -> row t>>2, 32 cols
  {
    int row = t >> 2, q = t & 3;
    const unsigned short* src = &xs[row][q*32];
    unsigned short* dst = yout + ((rowbase + row) << 7) + q*32;
    #pragma unroll
    for (int k2=0; k2<4; ++k2)
      *reinterpret_cast<uint4*>(dst + k2*8) = *reinterpret_cast<const uint4*>(src + k2*8);
  }
}

// ---------------- shortcut GEMM: feats(64) x Wsc^T -> sc f32 ----------------
__global__ __launch_bounds__(256) void sc_gemm(const float* __restrict__ featsT,
                                               const float* __restrict__ W,
                                               float* __restrict__ scout,
                                               float* __restrict__ partials){
  __shared__ __align__(16) unsigned short Wt[64][136];
  __shared__ __align__(16) unsigned short xs[64][72];
  int t = threadIdx.x, tx = t&15, ty = t>>4;
  int rowbase = blockIdx.x * 64;
  for (int it=0; it<32; ++it){
    int flat = it*256 + t;
    int o = flat>>6, c = flat&63;
    Wt[c][o] = bfr(W[flat]);
  }
  for (int it=0; it<16; ++it){
    int flat = it*256 + t;
    int r = flat>>6, c = flat&63;
    xs[r][c] = bfr(featsT[(size_t)(rowbase + r)*64 + c]);
  }
  __syncthreads();
  float acc[4][8] = {};
  for (int c=0;c<64;++c){
    uint4 wv = *reinterpret_cast<const uint4*>(&Wt[c][tx*8]);
    float w[8];
    w[0]=bl(wv.x); w[1]=bh(wv.x); w[2]=bl(wv.y); w[3]=bh(wv.y);
    w[4]=bl(wv.z); w[5]=bh(wv.z); w[6]=bl(wv.w); w[7]=bh(wv.w);
    #pragma unroll
    for (int i=0;i<4;++i){
      float xv = bl((unsigned)xs[ty*4+i][c]);
      #pragma unroll
      for (int j=0;j<8;++j) acc[i][j] = fmaf(xv, w[j], acc[i][j]);
    }
  }
  #pragma unroll
  for (int i=0;i<4;++i)
    #pragma unroll
    for (int j=0;j<8;++j)
      scout[(size_t)(rowbase + ty*4 + i)*128 + tx*8 + j] = acc[i][j];

  __syncthreads();
  float* red = reinterpret_cast<float*>(&xs[0][0]);
  #pragma unroll
  for (int j=0;j<8;++j){
    float s=0.f;
    #pragma unroll
    for (int i=0;i<4;++i) s += acc[i][j];
    red[ty*128 + tx*8 + j] = s;
  }
  __syncthreads();
  if (t<128){
    float s=0.f;
    for (int y2=0;y2<16;++y2) s += red[y2*128 + t];
    partials[(size_t)blockIdx.x*256 + t] = s;
  }
  __syncthreads();
  #pragma unroll
  for (int j=0;j<8;++j){
    float s=0.f;
    #pragma unroll
    for (int i=0;i<4;++i) s += acc[i][j]*acc[i][j];
    red[ty*128 + tx*8 + j] = s;
  }
  __syncthreads();
  if (t<128){
    float s=0.f;
    for (int y2=0;y2<16;++y2) s += red[y2*128 + t];
    partials[(size_t)blockIdx.x*256 + 128 + t] = s;
  }
}

// ---------------- deterministic stat reduction ----------------
__global__ __launch_bounds__(256) void reduce_stage1(const float* __restrict__ partials,
                                                     float* __restrict__ out, int rows){
  int t = threadIdx.x;
  size_t base = (size_t)blockIdx.x * rows * 256;
  float acc = 0.f;
  for (int r=0;r<rows;++r) acc += partials[base + (size_t)r*256 + t];
  out[blockIdx.x*256 + t] = acc;
}

__global__ __launch_bounds__(256) void finalize_stats(const float* __restrict__ s1, int g1,
                                                      float inv_count,
                                                      const float* __restrict__ g,
                                                      const float* __restrict__ beta,
                                                      float* __restrict__ sb){
  int t = threadIdx.x;
  float acc = 0.f;
  for (int j=0;j<g1;++j) acc += s1[j*256 + t];
  __shared__ float tot[256];
  tot[t] = acc;
  __syncthreads();
  if (t < 128){
    float mean = tot[t] * inv_count;
    float var  = tot[128+t] * inv_count - mean*mean;
    var = fmaxf(var, 0.f);
    float rstd = 1.0f / sqrtf(var + 1e-5f);
    float s = g[t] * rstd;
    sb[t] = s;
    sb[128+t] = beta[t] - mean*s;
  }
}

// ---------------- final: out = relu(bn_sc(sc) + mean_k relu(bn2(y2))) , transposed ----------------
__global__ __launch_bounds__(256) void final_kernel(const unsigned short* __restrict__ y2,
                                                    const float* __restrict__ sc,
                                                    const float* __restrict__ sb2,
                                                    const float* __restrict__ sbsc,
                                                    float* __restrict__ out){
  __shared__ __align__(16) float obuf[128][66];
  int t = threadIdx.x;
  int b = blockIdx.x >> 4;
  int n0 = (blockIdx.x & 15) * 64;
  int o = t & 127, half = t >> 7;
  float s2 = sb2[o], c2 = sb2[128+o];
  float ss = sbsc[o], cs = sbsc[128+o];
  for (int nn=0; nn<64; nn+=2){
    int nl = nn + half;
    size_t row0 = ((size_t)((b<<10) + n0 + nl)) << 4;
    float acc = 0.f;
    #pragma unroll
    for (int k=0;k<16;++k){
      float v = bl((unsigned)y2[(row0 + k)*128 + o]);
      acc += fmaxf(fmaf(v, s2, c2), 0.f);
    }
    float fts = acc * (1.f/16.f);
    float scv = sc[(size_t)((b<<10) + n0 + nl)*128 + o];
    scv = fmaf(scv, ss, cs);
    obuf[o][nl] = fmaxf(scv + fts, 0.f);
  }
  __syncthreads();
  for (int it=0; it<32; ++it){
    int flat = it*256 + t;
    int oo = flat>>6, nl = flat&63;
    out[((size_t)b<<17) + (oo<<10) + n0 + nl] = obuf[oo][nl];
  }
}

extern "C" void kernel_launch(void* const* d_in, const int* in_sizes, int n_in,
                              void* d_out, int out_size, void* d_ws, size_t ws_size,
                              hipStream_t stream) {
  const float* points   = (const float*)d_in[0];
  const float* features = (const float*)d_in[1];
  const float* W0  = (const float*)d_in[2];
  const float* g0  = (const float*)d_in[3];
  const float* b0  = (const float*)d_in[4];
  const float* W1  = (const float*)d_in[5];
  const float* g1  = (const float*)d_in[6];
  const float* b1  = (const float*)d_in[7];
  const float* W2  = (const float*)d_in[8];
  const float* g2  = (const float*)d_in[9];
  const float* b2  = (const float*)d_in[10];
  const float* Wsc = (const float*)d_in[11];
  const float* gsc = (const float*)d_in[12];
  const float* bsc = (const float*)d_in[13];

  float* out = (float*)d_out;

  if (ws_size < WS_NEED){
    float v = (float)(ws_size >> 20);
    sentinel_kernel<<<(out_size + 255)/256, 256, 0, stream>>>(out, out_size, v);
    return;
  }

  char* ws = (char*)d_ws;
  float*          featsT = (float*)(ws + OFF_FT);
  int*            idx    = (int*)(ws + OFF_IDX);
  unsigned short* y      = (unsigned short*)(ws + OFF_Y);
  float*          scbuf  = (float*)(ws + OFF_SC);
  float*          part   = (float*)(ws + OFF_PART);
  float*          s1     = (float*)(ws + OFF_S1);
  float*          sb     = (float*)(ws + OFF_SB);

  transpose_feats<<<dim3(32,16), 256, 0, stream>>>(features, featsT);
  knn_kernel<<<dim3(32,32), 256, 0, stream>>>(points, idx);

  // layer 0 (gather + MFMA)
  gemm_mfma<0><<<NROW/64, 256, 57600, stream>>>(featsT, idx, nullptr, nullptr, W0, y, part);
  reduce_stage1<<<64, 256, 0, stream>>>(part, s1, 128);
  finalize_stats<<<1, 256, 0, stream>>>(s1, 64, 1.f/524288.f, g0, b0, sb + 0);
  // layer 1 (in-place MFMA)
  gemm_mfma<1><<<NROW/64, 256, 39936, stream>>>(nullptr, nullptr, y, sb + 0, W1, y, part);
  reduce_stage1<<<64, 256, 0, stream>>>(part, s1, 128);
  finalize_stats<<<1, 256, 0, stream>>>(s1, 64, 1.f/524288.f, g1, b1, sb + 256);
  // layer 2 (in-place MFMA)
  gemm_mfma<1><<<NROW/64, 256, 39936, stream>>>(nullptr, nullptr, y, sb + 256, W2, y, part);
  reduce_stage1<<<64, 256, 0, stream>>>(part, s1, 128);
  finalize_stats<<<1, 256, 0, stream>>>(s1, 64, 1.f/524288.f, g2, b2, sb + 512);
  // shortcut
  sc_gemm<<<NROWSC/64, 256, 0, stream>>>(featsT, Wsc, scbuf, part);
  reduce_stage1<<<8, 256, 0, stream>>>(part, s1, 64);
  finalize_stats<<<1, 256, 0, stream>>>(s1, 8, 1.f/32768.f, gsc, bsc, sb + 768);
  // fuse + transpose
  final_kernel<<<512, 256, 0, stream>>>(y, scbuf, sb + 512, sb + 768, out);
}